// Round 3
// baseline (2401.982 us; speedup 1.0000x reference)
//
#include <hip/hip_runtime.h>
#include <math.h>

#define BATCH 256

// x[256][P] -> xt[P][256], 64x64 LDS tiles
__global__ __launch_bounds__(256) void transpose_kernel(
    const float* __restrict__ x, float* __restrict__ xt, int P) {
  __shared__ float tile[64][65];
  int p0 = blockIdx.x * 64, b0 = blockIdx.y * 64;
  int tx = threadIdx.x & 63, ty = threadIdx.x >> 6;  // tx: 0..63, ty: 0..3
#pragma unroll
  for (int r = 0; r < 64; r += 4) {
    int pp = p0 + tx;
    if (pp < P) tile[tx][ty + r] = x[(size_t)(b0 + ty + r) * (size_t)P + pp];
  }
  __syncthreads();
#pragma unroll
  for (int r = 0; r < 64; r += 4) {
    int pl = ty + r, pp = p0 + pl;
    if (pp < P) xt[(size_t)pp * BATCH + b0 + tx] = tile[pl][tx];
  }
}

// Direct 4D conv + bias + relu, batch-innermost layout, h- and w-tiled.
// in : [CIN][TI][TI][TI][TI][256],  out: [COUT][WO][WO][WO][WO][256]
// Block: 256 threads (lane=b). Each block: HT output h positions x WT output
// w positions x CO_PER channels for one (t,d). HT|WO and WT|WO exactly ->
// no bounds guards anywhere. __launch_bounds__(256,4) caps VGPR at 128 so
// >=4 waves/SIMD are resident (round-2 lesson: 196 VGPR -> 10% occupancy).
// grid: x = HTILES * WTILES * (COUT/CO_PER), y = d, z = t.
template <int CIN, int COUT, int CO_PER, int KK, int TI, int HT, int WT>
__global__ __launch_bounds__(256, 4) void conv_relu(
    const float* __restrict__ xin, const float* __restrict__ wgt,
    const float* __restrict__ bias, float* __restrict__ out) {
  constexpr int WO = TI - KK + 1;
  constexpr int HTILES = WO / HT;
  constexpr int WTILES = WO / WT;
  constexpr int XV = WT + KK - 1;  // input row span per w-tile
  constexpr int K4 = KK * KK * KK * KK;
  constexpr int NWS = CO_PER * CIN * K4;
  constexpr int sH = TI * BATCH, sD = TI * TI * BATCH,
                sT = TI * TI * TI * BATCH, sC = TI * TI * TI * TI * BATCH;
  constexpr int oH = WO * BATCH, oD = WO * WO * BATCH,
                oT = WO * WO * WO * BATCH, oC = WO * WO * WO * WO * BATCH;

  const int htile = blockIdx.x % HTILES;
  const int wtile = (blockIdx.x / HTILES) % WTILES;
  const int cog = blockIdx.x / (HTILES * WTILES);
  const int co0 = cog * CO_PER;

  __shared__ float wl[NWS];
  for (int i = threadIdx.x; i < NWS; i += 256) wl[i] = wgt[co0 * CIN * K4 + i];
  __syncthreads();

  const int d = blockIdx.y, t = blockIdx.z;
  const int h0 = htile * HT, w0 = wtile * WT;
  const int b = threadIdx.x;

  float acc[HT][CO_PER][WT];
#pragma unroll
  for (int hh = 0; hh < HT; hh++)
#pragma unroll
    for (int co = 0; co < CO_PER; co++) {
      float bv = bias[co0 + co];
#pragma unroll
      for (int j = 0; j < WT; j++) acc[hh][co][j] = bv;
    }

#pragma unroll 1
  for (int ci = 0; ci < CIN; ci++)
#pragma unroll 1
    for (int kt = 0; kt < KK; kt++)
#pragma unroll 1
      for (int kd = 0; kd < KK; kd++) {
        const float* base =
            xin + ci * sC + (t + kt) * sT + (d + kd) * sD + w0 * BATCH + b;
#pragma unroll
        for (int r = 0; r < KK + HT - 1; r++) {
          const float* row = base + (h0 + r) * sH;
          float xv[XV];
#pragma unroll
          for (int j = 0; j < XV; j++) xv[j] = row[j * BATCH];  // coalesced
#pragma unroll
          for (int hh = 0; hh < HT; hh++) {
            const int kh = r - hh;  // compile-time after unroll
            if (kh >= 0 && kh < KK) {
#pragma unroll
              for (int co = 0; co < CO_PER; co++)
#pragma unroll
                for (int kw = 0; kw < KK; kw++) {
                  const float wv =
                      wl[((((co * CIN + ci) * KK + kt) * KK + kd) * KK + kh) * KK + kw];
#pragma unroll
                  for (int j = 0; j < WT; j++)
                    acc[hh][co][j] = fmaf(xv[j + kw], wv, acc[hh][co][j]);
                }
            }
          }
        }
      }

#pragma unroll
  for (int hh = 0; hh < HT; hh++)
#pragma unroll
    for (int co = 0; co < CO_PER; co++)
#pragma unroll
      for (int j = 0; j < WT; j++) {
        float v = acc[hh][co][j];
        v = v > 0.f ? v : 0.f;
        out[(co0 + co) * oC + t * oT + d * oD + (h0 + hh) * oH +
            (w0 + j) * BATCH + b] = v;
      }
}

// h5 is [1280][256] (k-major: co,t,d,h,w). One block per output neuron o.
__global__ __launch_bounds__(256) void fc1_kernel(
    const float* __restrict__ h, const float* __restrict__ w,
    const float* __restrict__ bias, float* __restrict__ out) {
  const int o = blockIdx.x, b = threadIdx.x;
  const float* wr = w + o * 1280;
  float a0 = 0.f, a1 = 0.f, a2 = 0.f, a3 = 0.f;
#pragma unroll 4
  for (int k = 0; k < 1280; k += 4) {
    a0 = fmaf(h[(k + 0) * BATCH + b], wr[k + 0], a0);
    a1 = fmaf(h[(k + 1) * BATCH + b], wr[k + 1], a1);
    a2 = fmaf(h[(k + 2) * BATCH + b], wr[k + 2], a2);
    a3 = fmaf(h[(k + 3) * BATCH + b], wr[k + 3], a3);
  }
  float acc = (a0 + a1) + (a2 + a3) + bias[o];
  out[o * BATCH + b] = acc > 0.f ? acc : 0.f;
}

// r: [33][256] -> d_out[256] = sigmoid(w.r + b)
__global__ __launch_bounds__(256) void fc2_kernel(
    const float* __restrict__ r, const float* __restrict__ w,
    const float* __restrict__ bias, float* __restrict__ out) {
  const int b = threadIdx.x;
  float acc = bias[0];
#pragma unroll
  for (int o = 0; o < 33; o++) acc = fmaf(r[o * BATCH + b], w[o], acc);
  out[b] = 1.f / (1.f + expf(-acc));
}

extern "C" void kernel_launch(void* const* d_in, const int* in_sizes, int n_in,
                              void* d_out, int out_size, void* d_ws, size_t ws_size,
                              hipStream_t stream) {
  const float* x    = (const float*)d_in[0];
  const float* w1   = (const float*)d_in[1];
  const float* b1   = (const float*)d_in[2];
  const float* w2   = (const float*)d_in[3];
  const float* b2   = (const float*)d_in[4];
  const float* w3   = (const float*)d_in[5];
  const float* b3   = (const float*)d_in[6];
  const float* w4   = (const float*)d_in[7];
  const float* b4   = (const float*)d_in[8];
  const float* w5   = (const float*)d_in[9];
  const float* b5   = (const float*)d_in[10];
  const float* fc1w = (const float*)d_in[11];
  const float* fc1b = (const float*)d_in[12];
  const float* fc2w = (const float*)d_in[13];
  const float* fc2b = (const float*)d_in[14];
  float* out = (float*)d_out;

  float* wsf = (float*)d_ws;
  float* R0 = wsf;
  float* R1 = wsf + 26873856;
  float* xt = R0;
  float* h1 = R1;
  float* h2 = R0;
  float* h3 = R1;
  float* h4 = R0;
  float* h5 = R1;
  float* fo = R0;

  const int P = 104976;  // 18^4
  transpose_kernel<<<dim3((P + 63) / 64, 4), 256, 0, stream>>>(x, xt, P);

  // <CIN, COUT, CO_PER, KK, TI, HT, WT>  grid(HTILES*WTILES*COUT/CO_PER, d, t)
  conv_relu<1, 3, 3, 4, 18, 3, 5><<<dim3(15, 15, 15), 256, 0, stream>>>(xt, w1, b1, h1);
  conv_relu<3, 3, 3, 4, 15, 2, 6><<<dim3(12, 12, 12), 256, 0, stream>>>(h1, w2, b2, h2);
  conv_relu<3, 4, 4, 4, 12, 3, 3><<<dim3(9, 9, 9), 256, 0, stream>>>(h2, w3, b3, h3);
  conv_relu<4, 5, 5, 4, 9, 1, 3><<<dim3(12, 6, 6), 256, 0, stream>>>(h3, w4, b4, h4);
  conv_relu<5, 5, 5, 3, 6, 1, 4><<<dim3(4, 4, 4), 256, 0, stream>>>(h4, w5, b5, h5);

  fc1_kernel<<<33, 256, 0, stream>>>(h5, fc1w, fc1b, fo);
  fc2_kernel<<<1, 256, 0, stream>>>(fo, fc2w, fc2b, out);
}

// Round 4
// 1236.078 us; speedup vs baseline: 1.9432x; 1.9432x over previous
//
#include <hip/hip_runtime.h>
#include <math.h>

#define BATCH 256

// x[256][P] -> xt[P][256], 64x64 LDS tiles
__global__ __launch_bounds__(256) void transpose_kernel(
    const float* __restrict__ x, float* __restrict__ xt, int P) {
  __shared__ float tile[64][65];
  int p0 = blockIdx.x * 64, b0 = blockIdx.y * 64;
  int tx = threadIdx.x & 63, ty = threadIdx.x >> 6;  // tx: 0..63, ty: 0..3
#pragma unroll
  for (int r = 0; r < 64; r += 4) {
    int pp = p0 + tx;
    if (pp < P) tile[tx][ty + r] = x[(size_t)(b0 + ty + r) * (size_t)P + pp];
  }
  __syncthreads();
#pragma unroll
  for (int r = 0; r < 64; r += 4) {
    int pl = ty + r, pp = p0 + pl;
    if (pp < P) xt[(size_t)pp * BATCH + b0 + tx] = tile[pl][tx];
  }
}

// Direct 4D conv + bias + relu, batch-innermost layout, h- and w-tiled with a
// sliding single-row window (load row once, apply to every valid (hh,kh)).
// in : [CIN][TI][TI][TI][TI][256],  out: [COUT][WO][WO][WO][WO][256]
// NO __launch_bounds__ min-wave forcing (round-3 lesson: capping the
// allocator caused 3.3 GB of scratch spills). Tiles sized so acc<=54 regs;
// HT|WO, WT|WO exactly -> no guards.
// grid: x = htile + HTILES*(wtile + WTILES*cog), y = d, z = t.
template <int CIN, int COUT, int CO_PER, int KK, int TI, int HT, int WT>
__global__ __launch_bounds__(256) void conv_relu(
    const float* __restrict__ xin, const float* __restrict__ wgt,
    const float* __restrict__ bias, float* __restrict__ out) {
  constexpr int WO = TI - KK + 1;
  constexpr int HTILES = WO / HT;
  constexpr int WTILES = WO / WT;
  constexpr int XV = WT + KK - 1;  // input row span per w-tile
  constexpr int K4 = KK * KK * KK * KK;
  constexpr int NWS = CO_PER * CIN * K4;
  constexpr int sH = TI * BATCH, sD = TI * TI * BATCH,
                sT = TI * TI * TI * BATCH, sC = TI * TI * TI * TI * BATCH;
  constexpr int oH = WO * BATCH, oD = WO * WO * BATCH,
                oT = WO * WO * WO * BATCH, oC = WO * WO * WO * WO * BATCH;

  const int htile = blockIdx.x % HTILES;
  const int wtile = (blockIdx.x / HTILES) % WTILES;
  const int cog = blockIdx.x / (HTILES * WTILES);
  const int co0 = cog * CO_PER;

  __shared__ float wl[NWS];
  for (int i = threadIdx.x; i < NWS; i += 256) wl[i] = wgt[co0 * CIN * K4 + i];
  __syncthreads();

  const int d = blockIdx.y, t = blockIdx.z;
  const int h0 = htile * HT, w0 = wtile * WT;
  const int b = threadIdx.x;

  float acc[HT][CO_PER][WT];
#pragma unroll
  for (int hh = 0; hh < HT; hh++)
#pragma unroll
    for (int co = 0; co < CO_PER; co++) {
      float bv = bias[co0 + co];
#pragma unroll
      for (int j = 0; j < WT; j++) acc[hh][co][j] = bv;
    }

#pragma unroll 1
  for (int ci = 0; ci < CIN; ci++)
#pragma unroll 1
    for (int kt = 0; kt < KK; kt++)
#pragma unroll 1
      for (int kd = 0; kd < KK; kd++) {
        const float* base =
            xin + ci * sC + (t + kt) * sT + (d + kd) * sD + w0 * BATCH + b;
#pragma unroll
        for (int r = 0; r < KK + HT - 1; r++) {
          const float* row = base + (h0 + r) * sH;
          float xv[XV];
#pragma unroll
          for (int j = 0; j < XV; j++) xv[j] = row[j * BATCH];  // coalesced
#pragma unroll
          for (int hh = 0; hh < HT; hh++) {
            const int kh = r - hh;  // compile-time after full unroll
            if (kh >= 0 && kh < KK) {
#pragma unroll
              for (int co = 0; co < CO_PER; co++)
#pragma unroll
                for (int kw = 0; kw < KK; kw++) {
                  const float wv =
                      wl[((((co * CIN + ci) * KK + kt) * KK + kd) * KK + kh) * KK + kw];
#pragma unroll
                  for (int j = 0; j < WT; j++)
                    acc[hh][co][j] = fmaf(xv[j + kw], wv, acc[hh][co][j]);
                }
            }
          }
        }
      }

#pragma unroll
  for (int hh = 0; hh < HT; hh++)
#pragma unroll
    for (int co = 0; co < CO_PER; co++)
#pragma unroll
      for (int j = 0; j < WT; j++) {
        float v = acc[hh][co][j];
        v = v > 0.f ? v : 0.f;
        out[(co0 + co) * oC + t * oT + d * oD + (h0 + hh) * oH +
            (w0 + j) * BATCH + b] = v;
      }
}

// h5 is [1280][256] (k-major: co,t,d,h,w). One block per output neuron o.
__global__ __launch_bounds__(256) void fc1_kernel(
    const float* __restrict__ h, const float* __restrict__ w,
    const float* __restrict__ bias, float* __restrict__ out) {
  const int o = blockIdx.x, b = threadIdx.x;
  const float* wr = w + o * 1280;
  float a0 = 0.f, a1 = 0.f, a2 = 0.f, a3 = 0.f;
#pragma unroll 4
  for (int k = 0; k < 1280; k += 4) {
    a0 = fmaf(h[(k + 0) * BATCH + b], wr[k + 0], a0);
    a1 = fmaf(h[(k + 1) * BATCH + b], wr[k + 1], a1);
    a2 = fmaf(h[(k + 2) * BATCH + b], wr[k + 2], a2);
    a3 = fmaf(h[(k + 3) * BATCH + b], wr[k + 3], a3);
  }
  float acc = (a0 + a1) + (a2 + a3) + bias[o];
  out[o * BATCH + b] = acc > 0.f ? acc : 0.f;
}

// r: [33][256] -> d_out[256] = sigmoid(w.r + b)
__global__ __launch_bounds__(256) void fc2_kernel(
    const float* __restrict__ r, const float* __restrict__ w,
    const float* __restrict__ bias, float* __restrict__ out) {
  const int b = threadIdx.x;
  float acc = bias[0];
#pragma unroll
  for (int o = 0; o < 33; o++) acc = fmaf(r[o * BATCH + b], w[o], acc);
  out[b] = 1.f / (1.f + expf(-acc));
}

extern "C" void kernel_launch(void* const* d_in, const int* in_sizes, int n_in,
                              void* d_out, int out_size, void* d_ws, size_t ws_size,
                              hipStream_t stream) {
  const float* x    = (const float*)d_in[0];
  const float* w1   = (const float*)d_in[1];
  const float* b1   = (const float*)d_in[2];
  const float* w2   = (const float*)d_in[3];
  const float* b2   = (const float*)d_in[4];
  const float* w3   = (const float*)d_in[5];
  const float* b3   = (const float*)d_in[6];
  const float* w4   = (const float*)d_in[7];
  const float* b4   = (const float*)d_in[8];
  const float* w5   = (const float*)d_in[9];
  const float* b5   = (const float*)d_in[10];
  const float* fc1w = (const float*)d_in[11];
  const float* fc1b = (const float*)d_in[12];
  const float* fc2w = (const float*)d_in[13];
  const float* fc2b = (const float*)d_in[14];
  float* out = (float*)d_out;

  float* wsf = (float*)d_ws;
  float* R0 = wsf;
  float* R1 = wsf + 26873856;
  float* xt = R0;
  float* h1 = R1;
  float* h2 = R0;
  float* h3 = R1;
  float* h4 = R0;
  float* h5 = R1;
  float* fo = R0;

  const int P = 104976;  // 18^4
  transpose_kernel<<<dim3((P + 63) / 64, 4), 256, 0, stream>>>(x, xt, P);

  // <CIN, COUT, CO_PER, KK, TI, HT, WT>  grid(HTILES*WTILES*COUT/CO_PER, d, t)
  // acc regs: c1=45 c2=54 c3=36 c4=15 c5=20 ; blocks: 3375/1152/729/432/64
  conv_relu<1, 3, 3, 4, 18, 3, 5><<<dim3(15, 15, 15), 256, 0, stream>>>(xt, w1, b1, h1);
  conv_relu<3, 3, 3, 4, 15, 3, 6><<<dim3(8, 12, 12), 256, 0, stream>>>(h1, w2, b2, h2);
  conv_relu<3, 4, 4, 4, 12, 3, 3><<<dim3(9, 9, 9), 256, 0, stream>>>(h2, w3, b3, h3);
  conv_relu<4, 5, 5, 4, 9, 1, 3><<<dim3(12, 6, 6), 256, 0, stream>>>(h3, w4, b4, h4);
  conv_relu<5, 5, 5, 3, 6, 1, 4><<<dim3(4, 4, 4), 256, 0, stream>>>(h4, w5, b5, h5);

  fc1_kernel<<<33, 256, 0, stream>>>(h5, fc1w, fc1b, fo);
  fc2_kernel<<<1, 256, 0, stream>>>(fo, fc2w, fc2b, out);
}

// Round 5
// 931.818 us; speedup vs baseline: 2.5777x; 1.3265x over previous
//
#include <hip/hip_runtime.h>
#include <math.h>

#define BATCH 256
typedef unsigned int uint;
typedef unsigned short ushort;
typedef _Float16 half2_t __attribute__((ext_vector_type(2)));

// v_dot2_f32_f16: c += a.x*b.x + a.y*b.y  (f16 mul, f32 accumulate)
__device__ __forceinline__ float dot2h(uint a, uint b, float c) {
#if __has_builtin(__builtin_amdgcn_fdot2)
  return __builtin_amdgcn_fdot2(__builtin_bit_cast(half2_t, a),
                                __builtin_bit_cast(half2_t, b), c, false);
#else
  half2_t av = __builtin_bit_cast(half2_t, a);
  half2_t bv = __builtin_bit_cast(half2_t, b);
  return c + (float)av[0] * (float)bv[0] + (float)av[1] * (float)bv[1];
#endif
}

__device__ __forceinline__ ushort f2h(float f) {
  _Float16 h = (_Float16)f;
  return __builtin_bit_cast(ushort, h);
}

// x fp32 [256][P] -> xt f16 [P][256], 64x64 LDS tiles
__global__ __launch_bounds__(256) void transpose_kernel(
    const float* __restrict__ x, ushort* __restrict__ xt, int P) {
  __shared__ float tile[64][65];
  int p0 = blockIdx.x * 64, b0 = blockIdx.y * 64;
  int tx = threadIdx.x & 63, ty = threadIdx.x >> 6;
#pragma unroll
  for (int r = 0; r < 64; r += 4) {
    int pp = p0 + tx;
    if (pp < P) tile[tx][ty + r] = x[(size_t)(b0 + ty + r) * (size_t)P + pp];
  }
  __syncthreads();
#pragma unroll
  for (int r = 0; r < 64; r += 4) {
    int pl = ty + r, pp = p0 + pl;
    if (pp < P) xt[(size_t)pp * BATCH + b0 + tx] = f2h(tile[pl][tx]);
  }
}

// Direct 4D conv + bias + relu, f16 activations (f32 accum), batch-innermost,
// h+w register tiling with sliding kh window. Inner product via v_dot2_f32_f16
// over kw pairs (2 MACs/instr -> 2x fp32 FMA rate).
// in : ushort f16 [CIN][TI][TI][TI][TI][256], out: ushort f16 [COUT][WO]^4[256]
// Weights fp32 global -> packed f16 pairs in LDS.
// R3 lesson: no min-wave launch_bounds (allocator spills). R4 tiling kept.
template <int CIN, int COUT, int CO_PER, int KK, int TI, int HT, int WT>
__global__ __launch_bounds__(256) void conv_relu(
    const ushort* __restrict__ xin, const float* __restrict__ wgt,
    const float* __restrict__ bias, ushort* __restrict__ out) {
  constexpr int WO = TI - KK + 1;
  constexpr int HTILES = WO / HT;
  constexpr int WTILES = WO / WT;
  constexpr int KWP = (KK + 1) / 2;        // kw pairs (odd KK zero-padded)
  constexpr int XV = WT + 2 * KWP - 1;     // input row span (pair-padded)
  constexpr int K3 = KK * KK * KK;
  constexpr int NWP = CO_PER * CIN * K3 * KWP;  // packed pairs in LDS
  constexpr int sH = TI * BATCH, sD = TI * TI * BATCH,
                sT = TI * TI * TI * BATCH, sC = TI * TI * TI * TI * BATCH;
  constexpr int oH = WO * BATCH, oD = WO * WO * BATCH,
                oT = WO * WO * WO * BATCH, oC = WO * WO * WO * WO * BATCH;

  const int htile = blockIdx.x % HTILES;
  const int wtile = (blockIdx.x / HTILES) % WTILES;
  const int cog = blockIdx.x / (HTILES * WTILES);
  const int co0 = cog * CO_PER;

  __shared__ uint wl[NWP];
  for (int i = threadIdx.x; i < NWP; i += 256) {
    // i = ((((co*CIN+ci)*KK+kt)*KK+kd)*KK+kh)*KWP + kwp
    int kwp = i % KWP;
    int r = i / KWP;
    int kh = r % KK; r /= KK;
    int kd = r % KK; r /= KK;
    int kt = r % KK; r /= KK;
    int ci = r % CIN;
    int co = r / CIN;
    int g = (((((co0 + co) * CIN + ci) * KK + kt) * KK + kd) * KK + kh) * KK + 2 * kwp;
    float w0f = wgt[g];
    float w1f = (2 * kwp + 1 < KK) ? wgt[g + 1] : 0.f;
    wl[i] = (uint)f2h(w0f) | ((uint)f2h(w1f) << 16);
  }
  __syncthreads();

  const int d = blockIdx.y, t = blockIdx.z;
  const int h0 = htile * HT, w0 = wtile * WT;
  const int b = threadIdx.x;

  float acc[HT][CO_PER][WT];
#pragma unroll
  for (int hh = 0; hh < HT; hh++)
#pragma unroll
    for (int co = 0; co < CO_PER; co++) {
      float bv = bias[co0 + co];
#pragma unroll
      for (int j = 0; j < WT; j++) acc[hh][co][j] = bv;
    }

#pragma unroll 1
  for (int ci = 0; ci < CIN; ci++)
#pragma unroll 1
    for (int kt = 0; kt < KK; kt++)
#pragma unroll 1
      for (int kd = 0; kd < KK; kd++) {
        const ushort* base =
            xin + ci * sC + (t + kt) * sT + (d + kd) * sD + w0 * BATCH + b;
#pragma unroll
        for (int r = 0; r < KK + HT - 1; r++) {
          const ushort* row = base + (h0 + r) * sH;
          uint xv[XV];
#pragma unroll
          for (int j = 0; j < XV; j++) xv[j] = (uint)row[j * BATCH];  // coalesced 2B/lane
          uint pk[XV - 1];  // pk[i] = (x[i], x[i+1]) as packed f16x2
#pragma unroll
          for (int i = 0; i < XV - 1; i++) pk[i] = xv[i] | (xv[i + 1] << 16);
#pragma unroll
          for (int hh = 0; hh < HT; hh++) {
            const int kh = r - hh;  // compile-time after full unroll
            if (kh >= 0 && kh < KK) {
#pragma unroll
              for (int co = 0; co < CO_PER; co++)
#pragma unroll
                for (int kwp = 0; kwp < KWP; kwp++) {
                  const uint wv =
                      wl[((((co * CIN + ci) * KK + kt) * KK + kd) * KK + kh) * KWP + kwp];
#pragma unroll
                  for (int j = 0; j < WT; j++)
                    acc[hh][co][j] = dot2h(pk[j + 2 * kwp], wv, acc[hh][co][j]);
                }
            }
          }
        }
      }

#pragma unroll
  for (int hh = 0; hh < HT; hh++)
#pragma unroll
    for (int co = 0; co < CO_PER; co++)
#pragma unroll
      for (int j = 0; j < WT; j++) {
        float v = acc[hh][co][j];
        v = v > 0.f ? v : 0.f;
        out[(co0 + co) * oC + t * oT + d * oD + (h0 + hh) * oH +
            (w0 + j) * BATCH + b] = f2h(v);
      }
}

// h5 f16 [1280][256] (k-major: co,t,d,h,w). One block per output neuron o.
__global__ __launch_bounds__(256) void fc1_kernel(
    const ushort* __restrict__ h, const float* __restrict__ w,
    const float* __restrict__ bias, float* __restrict__ out) {
  const int o = blockIdx.x, b = threadIdx.x;
  const float* wr = w + o * 1280;
  float a0 = 0.f, a1 = 0.f, a2 = 0.f, a3 = 0.f;
#pragma unroll 4
  for (int k = 0; k < 1280; k += 4) {
    a0 = fmaf((float)__builtin_bit_cast(_Float16, h[(k + 0) * BATCH + b]), wr[k + 0], a0);
    a1 = fmaf((float)__builtin_bit_cast(_Float16, h[(k + 1) * BATCH + b]), wr[k + 1], a1);
    a2 = fmaf((float)__builtin_bit_cast(_Float16, h[(k + 2) * BATCH + b]), wr[k + 2], a2);
    a3 = fmaf((float)__builtin_bit_cast(_Float16, h[(k + 3) * BATCH + b]), wr[k + 3], a3);
  }
  float acc = (a0 + a1) + (a2 + a3) + bias[o];
  out[o * BATCH + b] = acc > 0.f ? acc : 0.f;
}

// r: [33][256] -> d_out[256] = sigmoid(w.r + b)
__global__ __launch_bounds__(256) void fc2_kernel(
    const float* __restrict__ r, const float* __restrict__ w,
    const float* __restrict__ bias, float* __restrict__ out) {
  const int b = threadIdx.x;
  float acc = bias[0];
#pragma unroll
  for (int o = 0; o < 33; o++) acc = fmaf(r[o * BATCH + b], w[o], acc);
  out[b] = 1.f / (1.f + expf(-acc));
}

extern "C" void kernel_launch(void* const* d_in, const int* in_sizes, int n_in,
                              void* d_out, int out_size, void* d_ws, size_t ws_size,
                              hipStream_t stream) {
  const float* x    = (const float*)d_in[0];
  const float* w1   = (const float*)d_in[1];
  const float* b1   = (const float*)d_in[2];
  const float* w2   = (const float*)d_in[3];
  const float* b2   = (const float*)d_in[4];
  const float* w3   = (const float*)d_in[5];
  const float* b3   = (const float*)d_in[6];
  const float* w4   = (const float*)d_in[7];
  const float* b4   = (const float*)d_in[8];
  const float* w5   = (const float*)d_in[9];
  const float* b5   = (const float*)d_in[10];
  const float* fc1w = (const float*)d_in[11];
  const float* fc1b = (const float*)d_in[12];
  const float* fc2w = (const float*)d_in[13];
  const float* fc2b = (const float*)d_in[14];
  float* out = (float*)d_out;

  // Workspace: two ushort regions ping-pong (sizes halved vs fp32; keep
  // generous offsets). R0: xt,h2,h4 ; R1: h1,h3,h5 ; fc1out fp32 in R0.
  ushort* wsu = (ushort*)d_ws;
  ushort* R0 = wsu;
  ushort* R1 = wsu + 32000000;
  ushort* xt = R0;
  ushort* h1 = R1;
  ushort* h2 = R0;
  ushort* h3 = R1;
  ushort* h4 = R0;
  ushort* h5 = R1;
  float* fo = (float*)(wsu + 64000000);

  const int P = 104976;  // 18^4
  transpose_kernel<<<dim3((P + 63) / 64, 4), 256, 0, stream>>>(x, xt, P);

  // <CIN, COUT, CO_PER, KK, TI, HT, WT>  grid(HTILES*WTILES*COUT/CO_PER, d, t)
  // acc regs: c1=45 c2=54 c3=36 c4=15 c5=20 ; blocks: 3375/1152/729/432/64
  conv_relu<1, 3, 3, 4, 18, 3, 5><<<dim3(15, 15, 15), 256, 0, stream>>>(xt, w1, b1, h1);
  conv_relu<3, 3, 3, 4, 15, 3, 6><<<dim3(8, 12, 12), 256, 0, stream>>>(h1, w2, b2, h2);
  conv_relu<3, 4, 4, 4, 12, 3, 3><<<dim3(9, 9, 9), 256, 0, stream>>>(h2, w3, b3, h3);
  conv_relu<4, 5, 5, 4, 9, 1, 3><<<dim3(12, 6, 6), 256, 0, stream>>>(h3, w4, b4, h4);
  conv_relu<5, 5, 5, 3, 6, 1, 4><<<dim3(4, 4, 4), 256, 0, stream>>>(h4, w5, b5, h5);

  fc1_kernel<<<33, 256, 0, stream>>>(h5, fc1w, fc1b, fo);
  fc2_kernel<<<1, 256, 0, stream>>>(fo, fc2w, fc2b, out);
}